// Round 3
// baseline (718.712 us; speedup 1.0000x reference)
//
#include <hip/hip_runtime.h>

#define N_NODES  100000
#define N_EDGES  3200000
#define D_IN     128
#define ATT      64
#define HEADS    4
#define DK       16

// ---------------------------------------------------------------------------
// All tensors are FLOAT32 (per the reference: jnp.float32; harness rule
// "float32 -> const float*"). edge is int32 (JAX x64-disabled downcasts the
// int64 request). d_out is float32.
//
// Output regions (floats): att A[0,12.8M) | v V[12.8M,19.2M) | prods P[19.2M,32M)
// Staging plan (no d_ws dependency at all):
//   q -> A[0,6.4M), k -> A[6.4M,12.8M)      (att is written only by pass 2)
//   node_sum (400K f32) -> start of V        (v is projected LAST, overwriting)
// ---------------------------------------------------------------------------

// q = x@WQ+bQ, k = x@WK+bK. One wave per node, lane = output column.
__global__ __launch_bounds__(256) void proj_qk(
    const float* __restrict__ x,
    const float* __restrict__ WQ, const float* __restrict__ bQ,
    const float* __restrict__ WK, const float* __restrict__ bK,
    float* __restrict__ q_tmp, float* __restrict__ k_tmp)
{
    __shared__ float xs[4][D_IN];
    const int wave = threadIdx.x >> 6;
    const int lane = threadIdx.x & 63;
    const int node = blockIdx.x * 4 + wave;   // grid = 25000 -> always < N_NODES

    const float2* xrow = (const float2*)(x + (size_t)node * D_IN);
    const float2 x2 = xrow[lane];
    xs[wave][2 * lane]     = x2.x;
    xs[wave][2 * lane + 1] = x2.y;
    __syncthreads();

    float aq = bQ[lane];
    float ak = bK[lane];
#pragma unroll 8
    for (int i = 0; i < D_IN; ++i) {
        const float xv = xs[wave][i];
        aq = fmaf(xv, WQ[i * ATT + lane], aq);
        ak = fmaf(xv, WK[i * ATT + lane], ak);
    }
    const size_t base = (size_t)node * ATT;
    q_tmp[base + lane] = aq;
    k_tmp[base + lane] = ak;
}

// v = x@WV+bV, written transposed: v_out[n, d, h] = v[n][h*16+d].
// Runs LAST (overwrites the node_sum scratch living in this region).
__global__ __launch_bounds__(256) void proj_v(
    const float* __restrict__ x,
    const float* __restrict__ WV, const float* __restrict__ bV,
    float* __restrict__ v_out)
{
    __shared__ float xs[4][D_IN];
    const int wave = threadIdx.x >> 6;
    const int lane = threadIdx.x & 63;
    const int node = blockIdx.x * 4 + wave;

    const float2* xrow = (const float2*)(x + (size_t)node * D_IN);
    const float2 x2 = xrow[lane];
    xs[wave][2 * lane]     = x2.x;
    xs[wave][2 * lane + 1] = x2.y;
    __syncthreads();

    float av = bV[lane];
#pragma unroll 8
    for (int i = 0; i < D_IN; ++i)
        av = fmaf(xs[wave][i], WV[i * ATT + lane], av);

    const int d = lane & 15;
    const int h = lane >> 4;
    v_out[(size_t)node * ATT + d * HEADS + h] = av;
}

// One thread per (edge, head): gather 64 B q-slice + 64 B k-slice, dot,
// scale 1/sqrt(16)=0.25, write prods, accumulate exp(p) per (src,head).
// No max-shift: |p| <~ 1, exp perfectly conditioned; exp(p-m)/sum == exp(p)/sum.
__global__ __launch_bounds__(256) void edge_pass1(
    const int* __restrict__ edge,
    const float* __restrict__ q_tmp,
    const float* __restrict__ k_tmp,
    float* __restrict__ node_sum,
    float* __restrict__ prods_out)
{
    const int gid = blockIdx.x * blockDim.x + threadIdx.x;  // E*HEADS exact
    const int e = gid >> 2;
    const int h = gid & 3;

    const int s = edge[e];
    const int d = edge[N_EDGES + e];

    const float4* qr = (const float4*)(q_tmp + (size_t)s * ATT + h * DK);
    const float4* kr = (const float4*)(k_tmp + (size_t)d * ATT + h * DK);

    const float4 q0 = qr[0], q1 = qr[1], q2 = qr[2], q3 = qr[3];
    const float4 k0 = kr[0], k1 = kr[1], k2 = kr[2], k3 = kr[3];

    float acc = q0.x * k0.x + q0.y * k0.y + q0.z * k0.z + q0.w * k0.w;
    acc += q1.x * k1.x + q1.y * k1.y + q1.z * k1.z + q1.w * k1.w;
    acc += q2.x * k2.x + q2.y * k2.y + q2.z * k2.z + q2.w * k2.w;
    acc += q3.x * k3.x + q3.y * k3.y + q3.z * k3.z + q3.w * k3.w;
    const float p = acc * 0.25f;

    prods_out[gid] = p;
    atomicAdd(&node_sum[s * HEADS + h], __expf(p));
}

// attention[e,h] = exp(p) / (sum[src,h] + 1e-16). Overwrites q/k staging.
__global__ __launch_bounds__(256) void edge_pass2(
    const int* __restrict__ edge,
    const float* __restrict__ prods_out,
    const float* __restrict__ node_sum,
    float* __restrict__ att_out)
{
    const int gid = blockIdx.x * blockDim.x + threadIdx.x;
    const int e = gid >> 2;
    const int h = gid & 3;

    const int s = edge[e];
    const float p = prods_out[gid];
    att_out[gid] = __expf(p) / (node_sum[s * HEADS + h] + 1e-16f);
}

extern "C" void kernel_launch(void* const* d_in, const int* in_sizes, int n_in,
                              void* d_out, int out_size, void* d_ws, size_t ws_size,
                              hipStream_t stream) {
    const float* x  = (const float*)d_in[0];
    const int*   eg = (const int*)d_in[1];
    const float* WQ = (const float*)d_in[2];
    const float* bQ = (const float*)d_in[3];
    const float* WK = (const float*)d_in[4];
    const float* bK = (const float*)d_in[5];
    const float* WV = (const float*)d_in[6];
    const float* bV = (const float*)d_in[7];

    float* out       = (float*)d_out;
    float* att_out   = out;                               // [E, 4]     12.8M
    float* v_out     = out + (size_t)N_EDGES * HEADS;     // [N, 16, 4]  6.4M
    float* prods_out = v_out + (size_t)N_NODES * ATT;     // [E, 4]     12.8M

    // q/k staged inside the attention region (written only by pass 2)
    float* q_tmp = out;                                   // [0, 6.4M)
    float* k_tmp = out + (size_t)N_NODES * ATT;           // [6.4M, 12.8M)
    // softmax denominators staged inside the v region (v projected last)
    float* node_sum = v_out;                              // 400K floats

    hipMemsetAsync(node_sum, 0, (size_t)N_NODES * HEADS * sizeof(float), stream);

    proj_qk<<<N_NODES / 4, 256, 0, stream>>>(x, WQ, bQ, WK, bK, q_tmp, k_tmp);

    const int nthreads = N_EDGES * HEADS;                 // 12,800,000
    edge_pass1<<<nthreads / 256, 256, 0, stream>>>(eg, q_tmp, k_tmp, node_sum, prods_out);
    edge_pass2<<<nthreads / 256, 256, 0, stream>>>(eg, prods_out, node_sum, att_out);

    proj_v<<<N_NODES / 4, 256, 0, stream>>>(x, WV, bV, v_out);
}

// Round 4
// 514.478 us; speedup vs baseline: 1.3970x; 1.3970x over previous
//
#include <hip/hip_runtime.h>
#include <hip/hip_bf16.h>

#define N_NODES  100000
#define N_EDGES  3200000
#define D_IN     128
#define ATT      64
#define HEADS    4
#define DK       16
#define NPB      16   // nodes per block in proj

// ---------------------------------------------------------------------------
// fp32 in/out. q/k staged as BF16 (halves the random-gather footprint:
// 51.2 MB -> 25.6 MB table, one 128B line per row). Accuracy cost ~3e-4 on
// prods vs threshold 2.5e-2 (current margin 6x).
//
// Staging: Path A (ws_size >= 27.2 MB): q/k tables + node_sum in d_ws,
//   single fused projection kernel (one read of x).
// Path B (tiny ws): q/k inside att output region (written only by pass2),
//   node_sum at start of v region, v projected last. Branch is on ws_size
//   only -> identical work every call (graph-capture safe).
// ---------------------------------------------------------------------------

template<bool DO_QK, bool DO_V>
__global__ __launch_bounds__(256) void proj_kernel(
    const float* __restrict__ x,
    const float* __restrict__ WQ, const float* __restrict__ bQ,
    const float* __restrict__ WK, const float* __restrict__ bK,
    const float* __restrict__ WV, const float* __restrict__ bV,
    __hip_bfloat16* __restrict__ q_bf,
    __hip_bfloat16* __restrict__ k_bf,
    float* __restrict__ v_out)
{
    __shared__ float xs[NPB][D_IN];
    const int tid  = threadIdx.x;
    const int wave = tid >> 6;
    const int lane = tid & 63;          // output column c = h*16+d
    const int nbase = blockIdx.x * NPB; // grid = 6250 -> nbase+15 < N_NODES

    // cooperative stage of 16 x-rows (2048 contiguous floats) via float4
    const float4* xsrc = (const float4*)(x + (size_t)nbase * D_IN);
    float4* xdst = (float4*)&xs[0][0];
    xdst[tid]       = xsrc[tid];
    xdst[tid + 256] = xsrc[tid + 256];
    __syncthreads();

    const int n0 = wave * 4;            // this wave's 4 local nodes

    float aq[4], ak[4], av[4];
#pragma unroll
    for (int n = 0; n < 4; ++n) {
        if (DO_QK) { aq[n] = bQ[lane]; ak[n] = bK[lane]; }
        if (DO_V)  { av[n] = bV[lane]; }
    }

#pragma unroll 8
    for (int i = 0; i < D_IN; ++i) {
        float wq = 0.f, wk = 0.f, wv = 0.f;
        if (DO_QK) { wq = WQ[i * ATT + lane]; wk = WK[i * ATT + lane]; }
        if (DO_V)  { wv = WV[i * ATT + lane]; }
#pragma unroll
        for (int n = 0; n < 4; ++n) {
            const float xv = xs[n0 + n][i];
            if (DO_QK) { aq[n] = fmaf(xv, wq, aq[n]); ak[n] = fmaf(xv, wk, ak[n]); }
            if (DO_V)  { av[n] = fmaf(xv, wv, av[n]); }
        }
    }

    const int d = lane & 15;
    const int h = lane >> 4;
#pragma unroll
    for (int n = 0; n < 4; ++n) {
        const size_t base = (size_t)(nbase + n0 + n) * ATT;
        if (DO_QK) {
            q_bf[base + lane] = __float2bfloat16(aq[n]);
            k_bf[base + lane] = __float2bfloat16(ak[n]);
        }
        if (DO_V) v_out[base + d * HEADS + h] = av[n];
    }
}

// One thread per (edge, head): 32 B q-slice + 32 B k-slice (bf16), fp32 dot,
// scale 1/sqrt(16)=0.25, write prods, atomic-accumulate exp(p) per (src,h).
// No max-shift needed: |p| <~ 1, exp(p-m)/sum == exp(p)/sum exactly.
__global__ __launch_bounds__(256) void edge_pass1(
    const int* __restrict__ edge,
    const __hip_bfloat16* __restrict__ q_bf,
    const __hip_bfloat16* __restrict__ k_bf,
    float* __restrict__ node_sum,
    float* __restrict__ prods_out)
{
    const int gid = blockIdx.x * 256 + threadIdx.x;  // exactly E*HEADS
    const int e = gid >> 2;
    const int h = gid & 3;

    const int s = edge[e];
    const int d = edge[N_EDGES + e];

    union BF8 { float4 f4; __hip_bfloat162 h2[4]; };
    BF8 q0, q1, k0, k1;
    const float4* qr = (const float4*)(q_bf + (size_t)s * ATT + h * DK);
    const float4* kr = (const float4*)(k_bf + (size_t)d * ATT + h * DK);
    q0.f4 = qr[0]; q1.f4 = qr[1];
    k0.f4 = kr[0]; k1.f4 = kr[1];

    float acc = 0.f;
#pragma unroll
    for (int j = 0; j < 4; ++j) {
        acc += __bfloat162float(q0.h2[j].x) * __bfloat162float(k0.h2[j].x);
        acc += __bfloat162float(q0.h2[j].y) * __bfloat162float(k0.h2[j].y);
        acc += __bfloat162float(q1.h2[j].x) * __bfloat162float(k1.h2[j].x);
        acc += __bfloat162float(q1.h2[j].y) * __bfloat162float(k1.h2[j].y);
    }
    const float p = acc * 0.25f;

    prods_out[gid] = p;
    atomicAdd(&node_sum[s * HEADS + h], __expf(p));
}

// One thread per EDGE, all 4 heads via float4: att = exp(p)/(sum[src]+1e-16)
__global__ __launch_bounds__(256) void edge_pass2(
    const int* __restrict__ edge,
    const float* __restrict__ prods_out,
    const float* __restrict__ node_sum,
    float* __restrict__ att_out)
{
    const int e = blockIdx.x * 256 + threadIdx.x;    // exactly E
    const int s = edge[e];
    const float4 p  = ((const float4*)prods_out)[e];
    const float4 sm = ((const float4*)node_sum)[s];
    float4 a;
    a.x = __expf(p.x) / (sm.x + 1e-16f);
    a.y = __expf(p.y) / (sm.y + 1e-16f);
    a.z = __expf(p.z) / (sm.z + 1e-16f);
    a.w = __expf(p.w) / (sm.w + 1e-16f);
    ((float4*)att_out)[e] = a;
}

extern "C" void kernel_launch(void* const* d_in, const int* in_sizes, int n_in,
                              void* d_out, int out_size, void* d_ws, size_t ws_size,
                              hipStream_t stream) {
    const float* x  = (const float*)d_in[0];
    const int*   eg = (const int*)d_in[1];
    const float* WQ = (const float*)d_in[2];
    const float* bQ = (const float*)d_in[3];
    const float* WK = (const float*)d_in[4];
    const float* bK = (const float*)d_in[5];
    const float* WV = (const float*)d_in[6];
    const float* bV = (const float*)d_in[7];

    float* out       = (float*)d_out;
    float* att_out   = out;                               // [E, 4]     12.8M f
    float* v_out     = out + (size_t)N_EDGES * HEADS;     // [N, 16, 4]  6.4M f
    float* prods_out = v_out + (size_t)N_NODES * ATT;     // [E, 4]     12.8M f

    const size_t QK_ELEMS = (size_t)N_NODES * ATT;        // 6.4M per table
    const size_t QK_BYTES = QK_ELEMS * 2 * sizeof(__hip_bfloat16); // 25.6 MB
    const size_t SUM_BYTES = (size_t)N_NODES * HEADS * sizeof(float); // 1.6 MB

    const int proj_blocks  = N_NODES / NPB;               // 6250
    const int pass1_blocks = (N_EDGES * HEADS) / 256;     // 50000
    const int pass2_blocks = N_EDGES / 256;               // 12500

    if (ws_size >= QK_BYTES + SUM_BYTES) {
        // ---- Path A: everything in workspace, single fused projection ----
        __hip_bfloat16* q_bf = (__hip_bfloat16*)d_ws;
        __hip_bfloat16* k_bf = q_bf + QK_ELEMS;
        float* node_sum = (float*)((char*)d_ws + QK_BYTES);

        hipMemsetAsync(node_sum, 0, SUM_BYTES, stream);
        proj_kernel<true, true><<<proj_blocks, 256, 0, stream>>>(
            x, WQ, bQ, WK, bK, WV, bV, q_bf, k_bf, v_out);
        edge_pass1<<<pass1_blocks, 256, 0, stream>>>(eg, q_bf, k_bf, node_sum, prods_out);
        edge_pass2<<<pass2_blocks, 256, 0, stream>>>(eg, prods_out, node_sum, att_out);
    } else {
        // ---- Path B: stage q/k inside att region, node_sum in v region ----
        __hip_bfloat16* q_bf = (__hip_bfloat16*)att_out;  // first 25.6MB of 51.2MB
        __hip_bfloat16* k_bf = q_bf + QK_ELEMS;
        float* node_sum = v_out;

        hipMemsetAsync(node_sum, 0, SUM_BYTES, stream);
        proj_kernel<true, false><<<proj_blocks, 256, 0, stream>>>(
            x, WQ, bQ, WK, bK, WV, bV, q_bf, k_bf, v_out);
        edge_pass1<<<pass1_blocks, 256, 0, stream>>>(eg, q_bf, k_bf, node_sum, prods_out);
        edge_pass2<<<pass2_blocks, 256, 0, stream>>>(eg, prods_out, node_sum, att_out);
        proj_kernel<false, true><<<proj_blocks, 256, 0, stream>>>(
            x, WQ, bQ, WK, bK, WV, bV, q_bf, k_bf, v_out);
    }
}

// Round 5
// 397.854 us; speedup vs baseline: 1.8065x; 1.2931x over previous
//
#include <hip/hip_runtime.h>
#include <hip/hip_bf16.h>

#define N_NODES  100000
#define N_EDGES  3200000
#define D_IN     128
#define ATT      64
#define HEADS    4
#define DK       16
#define NPB      16    // nodes per block in fallback proj
#define XPAD     136   // LDS row stride (bf16 elems) for 32x128 x-tile: breaks 16-way bank conflict

typedef __attribute__((ext_vector_type(8))) short  bf16x8;  // 8 bf16 = 4 VGPRs
typedef __attribute__((ext_vector_type(4))) float  f32x4;

static __device__ inline unsigned short f2b(float f) {
    __hip_bfloat16 h = __float2bfloat16(f);
    return *reinterpret_cast<unsigned short*>(&h);
}

// ---------------------------------------------------------------------------
// Pre-kernel: Wt[mat*64+c][i] = bf16(W_mat[i*64+c]), mat in {Q,K,V}.
// 24576 elems, grid 96 x 256. W tables are 32KB each -> L2-hot.
// ---------------------------------------------------------------------------
__global__ __launch_bounds__(256) void w_to_bf16(
    const float* __restrict__ WQ, const float* __restrict__ WK,
    const float* __restrict__ WV, unsigned short* __restrict__ Wt)
{
    const int o   = blockIdx.x * 256 + threadIdx.x;  // 0..24575
    const int mat = o >> 13;
    const int r   = o & 8191;
    const int c   = r >> 7;     // 0..63
    const int i   = r & 127;    // 0..127
    const float* W = (mat == 0) ? WQ : ((mat == 1) ? WK : WV);
    Wt[o] = f2b(W[i * ATT + c]);
}

// ---------------------------------------------------------------------------
// MFMA projection: per block, 32 nodes x 192 output cols = [32x128]@[128x192].
// x-tile staged bf16 in LDS (padded); B-fragments read straight from global Wt
// (each block reads 48KB, disjoint per wave, L2-resident).
// Wave w owns N-tiles {3w..3w+2} x M-tiles {0,1}: 24 MFMA (16x16x32 bf16).
// D layout (m89-verified): col = lane&15, row = (lane>>4)*4 + reg.
// A-frag: A[m=lane&15][k=quad*8+j]; B-frag: B[k=quad*8+j][n=lane&15].
// ---------------------------------------------------------------------------
__global__ __launch_bounds__(256) void proj_mfma(
    const float* __restrict__ x,
    const unsigned short* __restrict__ Wt,
    const float* __restrict__ bQ, const float* __restrict__ bK,
    const float* __restrict__ bV,
    unsigned short* __restrict__ q_bf,
    unsigned short* __restrict__ k_bf,
    float* __restrict__ v_out)
{
    __shared__ unsigned short xls[32 * XPAD];  // 8704 B
    const int tid   = threadIdx.x;
    const int nbase = blockIdx.x * 32;         // grid 3125 -> exact

    // stage 32 x-rows (4096 f32) -> bf16 LDS, 4 float4 per thread
    const float4* xsrc = (const float4*)(x + (size_t)nbase * D_IN);
#pragma unroll
    for (int t = 0; t < 4; ++t) {
        const int c   = tid + 256 * t;         // 0..1023
        const int row = c >> 5;
        const int off = (c & 31) * 4;
        const float4 f = xsrc[c];
        ushort4 u;
        u.x = f2b(f.x); u.y = f2b(f.y); u.z = f2b(f.z); u.w = f2b(f.w);
        *(ushort4*)(xls + row * XPAD + off) = u;
    }
    __syncthreads();

    const int wave  = tid >> 6;
    const int lane  = tid & 63;
    const int row16 = lane & 15;
    const int quad  = lane >> 4;

    f32x4 acc[2][3];
#pragma unroll
    for (int m = 0; m < 2; ++m)
#pragma unroll
        for (int t = 0; t < 3; ++t)
            acc[m][t] = (f32x4){0.f, 0.f, 0.f, 0.f};

#pragma unroll
    for (int ks = 0; ks < 4; ++ks) {           // k0 = ks*32
        const int koff = ks * 32 + quad * 8;
        const bf16x8 a0 = *(const bf16x8*)(xls + (row16)      * XPAD + koff);
        const bf16x8 a1 = *(const bf16x8*)(xls + (16 + row16) * XPAD + koff);
#pragma unroll
        for (int t = 0; t < 3; ++t) {
            const int nrow = (wave * 3 + t) * 16 + row16;   // 0..191
            const bf16x8 b = *(const bf16x8*)(Wt + (size_t)nrow * D_IN + koff);
            acc[0][t] = __builtin_amdgcn_mfma_f32_16x16x32_bf16(a0, b, acc[0][t], 0, 0, 0);
            acc[1][t] = __builtin_amdgcn_mfma_f32_16x16x32_bf16(a1, b, acc[1][t], 0, 0, 0);
        }
    }

    // epilogue: bias + scatter. ntile/mat are wave-uniform (no divergence).
#pragma unroll
    for (int t = 0; t < 3; ++t) {
        const int ntile = wave * 3 + t;        // 0..11
        const int mat   = ntile >> 2;          // 0:Q 1:K 2:V
        const int ccb   = (ntile & 3) * 16 + row16;  // 0..63
        const float bias = (mat == 0) ? bQ[ccb] : ((mat == 1) ? bK[ccb] : bV[ccb]);
#pragma unroll
        for (int m = 0; m < 2; ++m) {
#pragma unroll
            for (int r = 0; r < 4; ++r) {
                const int node = nbase + m * 16 + quad * 4 + r;
                const float val = acc[m][t][r] + bias;
                if (mat == 0) {
                    q_bf[(size_t)node * ATT + ccb] = f2b(val);
                } else if (mat == 1) {
                    k_bf[(size_t)node * ATT + ccb] = f2b(val);
                } else {
                    // v_out[n, d, h] with cc = h*16+d
                    v_out[(size_t)node * ATT + (ccb & 15) * HEADS + (ccb >> 4)] = val;
                }
            }
        }
    }
}

// ---------------------------------------------------------------------------
// Fallback (Path B) projection — unchanged from R4.
// ---------------------------------------------------------------------------
template<bool DO_QK, bool DO_V>
__global__ __launch_bounds__(256) void proj_kernel(
    const float* __restrict__ x,
    const float* __restrict__ WQ, const float* __restrict__ bQ,
    const float* __restrict__ WK, const float* __restrict__ bK,
    const float* __restrict__ WV, const float* __restrict__ bV,
    __hip_bfloat16* __restrict__ q_bf,
    __hip_bfloat16* __restrict__ k_bf,
    float* __restrict__ v_out)
{
    __shared__ float xs[NPB][D_IN];
    const int tid  = threadIdx.x;
    const int wave = tid >> 6;
    const int lane = tid & 63;
    const int nbase = blockIdx.x * NPB;

    const float4* xsrc = (const float4*)(x + (size_t)nbase * D_IN);
    float4* xdst = (float4*)&xs[0][0];
    xdst[tid]       = xsrc[tid];
    xdst[tid + 256] = xsrc[tid + 256];
    __syncthreads();

    const int n0 = wave * 4;
    float aq[4], ak[4], av[4];
#pragma unroll
    for (int n = 0; n < 4; ++n) {
        if (DO_QK) { aq[n] = bQ[lane]; ak[n] = bK[lane]; }
        if (DO_V)  { av[n] = bV[lane]; }
    }
#pragma unroll 8
    for (int i = 0; i < D_IN; ++i) {
        float wq = 0.f, wk = 0.f, wv = 0.f;
        if (DO_QK) { wq = WQ[i * ATT + lane]; wk = WK[i * ATT + lane]; }
        if (DO_V)  { wv = WV[i * ATT + lane]; }
#pragma unroll
        for (int n = 0; n < 4; ++n) {
            const float xv = xs[n0 + n][i];
            if (DO_QK) { aq[n] = fmaf(xv, wq, aq[n]); ak[n] = fmaf(xv, wk, ak[n]); }
            if (DO_V)  { av[n] = fmaf(xv, wv, av[n]); }
        }
    }
    const int d = lane & 15;
    const int h = lane >> 4;
#pragma unroll
    for (int n = 0; n < 4; ++n) {
        const size_t base = (size_t)(nbase + n0 + n) * ATT;
        if (DO_QK) {
            q_bf[base + lane] = __float2bfloat16(aq[n]);
            k_bf[base + lane] = __float2bfloat16(ak[n]);
        }
        if (DO_V) v_out[base + d * HEADS + h] = av[n];
    }
}

// ---------------------------------------------------------------------------
// Edge pass 1 (unchanged): one thread per (edge, head); bf16 gathers, fp32 dot,
// atomic exp-sum per (src, head). No max-shift (|p| <~ 1, exactly equivalent).
// ---------------------------------------------------------------------------
__global__ __launch_bounds__(256) void edge_pass1(
    const int* __restrict__ edge,
    const __hip_bfloat16* __restrict__ q_bf,
    const __hip_bfloat16* __restrict__ k_bf,
    float* __restrict__ node_sum,
    float* __restrict__ prods_out)
{
    const int gid = blockIdx.x * 256 + threadIdx.x;
    const int e = gid >> 2;
    const int h = gid & 3;

    const int s = edge[e];
    const int d = edge[N_EDGES + e];

    union BF8 { float4 f4; __hip_bfloat162 h2[4]; };
    BF8 q0, q1, k0, k1;
    const float4* qr = (const float4*)(q_bf + (size_t)s * ATT + h * DK);
    const float4* kr = (const float4*)(k_bf + (size_t)d * ATT + h * DK);
    q0.f4 = qr[0]; q1.f4 = qr[1];
    k0.f4 = kr[0]; k1.f4 = kr[1];

    float acc = 0.f;
#pragma unroll
    for (int j = 0; j < 4; ++j) {
        acc += __bfloat162float(q0.h2[j].x) * __bfloat162float(k0.h2[j].x);
        acc += __bfloat162float(q0.h2[j].y) * __bfloat162float(k0.h2[j].y);
        acc += __bfloat162float(q1.h2[j].x) * __bfloat162float(k1.h2[j].x);
        acc += __bfloat162float(q1.h2[j].y) * __bfloat162float(k1.h2[j].y);
    }
    const float p = acc * 0.25f;

    prods_out[gid] = p;
    atomicAdd(&node_sum[s * HEADS + h], __expf(p));
}

// One thread per EDGE, 4 heads via float4.
__global__ __launch_bounds__(256) void edge_pass2(
    const int* __restrict__ edge,
    const float* __restrict__ prods_out,
    const float* __restrict__ node_sum,
    float* __restrict__ att_out)
{
    const int e = blockIdx.x * 256 + threadIdx.x;
    const int s = edge[e];
    const float4 p  = ((const float4*)prods_out)[e];
    const float4 sm = ((const float4*)node_sum)[s];
    float4 a;
    a.x = __expf(p.x) / (sm.x + 1e-16f);
    a.y = __expf(p.y) / (sm.y + 1e-16f);
    a.z = __expf(p.z) / (sm.z + 1e-16f);
    a.w = __expf(p.w) / (sm.w + 1e-16f);
    ((float4*)att_out)[e] = a;
}

extern "C" void kernel_launch(void* const* d_in, const int* in_sizes, int n_in,
                              void* d_out, int out_size, void* d_ws, size_t ws_size,
                              hipStream_t stream) {
    const float* x  = (const float*)d_in[0];
    const int*   eg = (const int*)d_in[1];
    const float* WQ = (const float*)d_in[2];
    const float* bQ = (const float*)d_in[3];
    const float* WK = (const float*)d_in[4];
    const float* bK = (const float*)d_in[5];
    const float* WV = (const float*)d_in[6];
    const float* bV = (const float*)d_in[7];

    float* out       = (float*)d_out;
    float* att_out   = out;                               // [E, 4]     12.8M f
    float* v_out     = out + (size_t)N_EDGES * HEADS;     // [N, 16, 4]  6.4M f
    float* prods_out = v_out + (size_t)N_NODES * ATT;     // [E, 4]     12.8M f

    const size_t QK_ELEMS  = (size_t)N_NODES * ATT;               // 6.4M per table
    const size_t QK_BYTES  = QK_ELEMS * 2 * sizeof(unsigned short); // 25.6 MB
    const size_t SUM_BYTES = (size_t)N_NODES * HEADS * sizeof(float); // 1.6 MB
    const size_t WT_BYTES  = (size_t)192 * D_IN * sizeof(unsigned short); // 48 KB

    const int pass1_blocks = (N_EDGES * HEADS) / 256;     // 50000
    const int pass2_blocks = N_EDGES / 256;               // 12500

    if (ws_size >= QK_BYTES + SUM_BYTES + WT_BYTES) {
        // ---- Path A (confirmed running in R4): all staging in d_ws ----
        unsigned short* q_bf = (unsigned short*)d_ws;
        unsigned short* k_bf = q_bf + QK_ELEMS;
        float* node_sum = (float*)((char*)d_ws + QK_BYTES);
        unsigned short* Wt = (unsigned short*)((char*)d_ws + QK_BYTES + SUM_BYTES);

        hipMemsetAsync(node_sum, 0, SUM_BYTES, stream);
        w_to_bf16<<<96, 256, 0, stream>>>(WQ, WK, WV, Wt);
        proj_mfma<<<N_NODES / 32, 256, 0, stream>>>(x, Wt, bQ, bK, bV,
                                                    q_bf, k_bf, v_out);
        edge_pass1<<<pass1_blocks, 256, 0, stream>>>(
            eg, (const __hip_bfloat16*)q_bf, (const __hip_bfloat16*)k_bf,
            node_sum, prods_out);
        edge_pass2<<<pass2_blocks, 256, 0, stream>>>(eg, prods_out, node_sum, att_out);
    } else {
        // ---- Path B fallback: stage in output regions (R4 logic) ----
        __hip_bfloat16* q_bf = (__hip_bfloat16*)att_out;
        __hip_bfloat16* k_bf = q_bf + QK_ELEMS;
        float* node_sum = v_out;

        hipMemsetAsync(node_sum, 0, SUM_BYTES, stream);
        proj_kernel<true, false><<<N_NODES / NPB, 256, 0, stream>>>(
            x, WQ, bQ, WK, bK, WV, bV, q_bf, k_bf, v_out);
        edge_pass1<<<pass1_blocks, 256, 0, stream>>>(eg, q_bf, k_bf, node_sum, prods_out);
        edge_pass2<<<pass2_blocks, 256, 0, stream>>>(eg, prods_out, node_sum, att_out);
        proj_kernel<false, true><<<N_NODES / NPB, 256, 0, stream>>>(
            x, WQ, bQ, WK, bK, WV, bV, q_bf, k_bf, v_out);
    }
}